// Round 1
// baseline (644.130 us; speedup 1.0000x reference)
//
#include <hip/hip_runtime.h>

// Problem constants
constexpr int N_TOK = 65536;        // 16*64*64 tokens
constexpr int D     = 64;           // embedding dim
constexpr int K     = 2048;         // codebook size
constexpr int KSPLIT = 2;           // split K for occupancy
constexpr int KHALF  = K / KSPLIT;  // 1024
constexpr int TILE_K = 128;         // codes per LDS tile (32 KB)

// Output layout (all float32, concatenated in reference return order)
constexpr size_t QN       = (size_t)N_TOK * D;   // 4194304 quantized
constexpr size_t SCAL_OFF = QN;                  // 5 scalars
constexpr size_t IDX_OFF  = QN + 5;              // 65536 indices (as float)
constexpr size_t PROB_OFF = IDX_OFF + N_TOK;     // 2048 avg_probs

// Workspace layout (bytes)
// 0       : cnorm   [K] float      (8192)
// 8192    : counts  [K] uint       (8192)
// 16384   : cand_dist [2*N] float  (524288)
// 540672  : cand_idx  [2*N] int    (524288)
// 1064960 : blocksums [256] double (2048)
constexpr size_t WS_CNORM = 0;
constexpr size_t WS_COUNT = 8192;
constexpr size_t WS_CDIST = 16384;
constexpr size_t WS_CIDX  = 540672;
constexpr size_t WS_BSUM  = 1064960;

__global__ __launch_bounds__(256) void vq_init(const float* __restrict__ emb,
                                               float* __restrict__ cnorm,
                                               unsigned* __restrict__ counts,
                                               double* __restrict__ blocksums) {
    int k = blockIdx.x * 256 + threadIdx.x;   // 0..2047
    const float4* row = (const float4*)(emb + (size_t)k * D);
    float s = 0.f;
#pragma unroll
    for (int i = 0; i < 16; ++i) {
        float4 v = row[i];
        s += v.x * v.x + v.y * v.y + v.z * v.z + v.w * v.w;
    }
    cnorm[k]  = s;
    counts[k] = 0u;
    if (k < 256) blocksums[k] = 0.0;
}

__global__ __launch_bounds__(256) void vq_dist(const float* __restrict__ x,
                                               const float* __restrict__ emb,
                                               const float* __restrict__ cnorm,
                                               float* __restrict__ cand_dist,
                                               int* __restrict__ cand_idx) {
    __shared__ float lds_c[TILE_K * D];   // 32 KB
    __shared__ float lds_n[TILE_K];

    const int half = blockIdx.x & 1;       // which K half
    const int tb   = blockIdx.x >> 1;      // token block 0..255
    const int t    = tb * 256 + threadIdx.x;

    // x row into registers (64 VGPRs)
    float xr[D];
    const float4* xrow = (const float4*)(x + (size_t)t * D);
#pragma unroll
    for (int i = 0; i < 16; ++i) {
        float4 v = xrow[i];
        xr[4 * i + 0] = v.x; xr[4 * i + 1] = v.y;
        xr[4 * i + 2] = v.z; xr[4 * i + 3] = v.w;
    }

    float best = 3.4e38f;
    int   bk   = 0;
    const int k0base = half * KHALF;

    for (int tile = 0; tile < KHALF / TILE_K; ++tile) {
        const int kbase = k0base + tile * TILE_K;
        __syncthreads();   // all readers of previous tile done
        // cooperative tile load: 2048 float4 / 256 threads = 8 each
        const float4* src = (const float4*)(emb + (size_t)kbase * D);
        float4* dst = (float4*)lds_c;
#pragma unroll
        for (int i = 0; i < (TILE_K * D / 4) / 256; ++i)
            dst[threadIdx.x + i * 256] = src[threadIdx.x + i * 256];
        if (threadIdx.x < TILE_K) lds_n[threadIdx.x] = cnorm[kbase + threadIdx.x];
        __syncthreads();

#pragma unroll 2
        for (int kk = 0; kk < TILE_K; ++kk) {
            const float* c = lds_c + kk * D;   // wave-uniform address -> LDS broadcast
            float s0 = 0.f, s1 = 0.f, s2 = 0.f, s3 = 0.f;
#pragma unroll
            for (int d = 0; d < D; d += 4) {
                s0 = fmaf(c[d + 0], xr[d + 0], s0);
                s1 = fmaf(c[d + 1], xr[d + 1], s1);
                s2 = fmaf(c[d + 2], xr[d + 2], s2);
                s3 = fmaf(c[d + 3], xr[d + 3], s3);
            }
            float dot  = (s0 + s1) + (s2 + s3);
            float dist = fmaf(-2.0f, dot, lds_n[kk]);   // ||c||^2 - 2 x.c
            if (dist < best) { best = dist; bk = kbase + kk; }  // strict < keeps first occurrence
        }
    }
    cand_dist[half * N_TOK + t] = best;
    cand_idx [half * N_TOK + t] = bk;
}

__global__ __launch_bounds__(256) void vq_epilogue(const float* __restrict__ x,
                                                   const float* __restrict__ emb,
                                                   const float* __restrict__ cand_dist,
                                                   const int* __restrict__ cand_idx,
                                                   unsigned* __restrict__ counts,
                                                   double* __restrict__ blocksums,
                                                   float* __restrict__ out) {
    const int t = blockIdx.x * 256 + threadIdx.x;
    float d0 = cand_dist[t];
    float d1 = cand_dist[N_TOK + t];
    int   k0 = cand_idx[t];
    int   k1 = cand_idx[N_TOK + t];
    // lower half wins ties -> matches first-occurrence argmin
    int bk = (d1 < d0) ? k1 : k0;

    out[IDX_OFF + t] = (float)bk;
    atomicAdd(&counts[bk], 1u);

    const float4* xrow = (const float4*)(x + (size_t)t * D);
    const float4* crow = (const float4*)(emb + (size_t)bk * D);
    float4* qrow = (float4*)(out + (size_t)t * D);

    float local = 0.f;
#pragma unroll
    for (int i = 0; i < 16; ++i) {
        float4 xv = xrow[i];
        float4 cv = crow[i];
        float dx = cv.x - xv.x, dy = cv.y - xv.y;
        float dz = cv.z - xv.z, dw = cv.w - xv.w;
        local += dx * dx + dy * dy + dz * dz + dw * dw;
        float4 q;
        q.x = xv.x + dx; q.y = xv.y + dy;   // straight-through: x + (q - x)
        q.z = xv.z + dz; q.w = xv.w + dw;
        qrow[i] = q;
    }

    // block-reduce (double) -> blocksums[blockIdx.x]
    double ld = (double)local;
#pragma unroll
    for (int off = 32; off > 0; off >>= 1) ld += __shfl_down(ld, off, 64);
    __shared__ double wsum[4];
    int lane = threadIdx.x & 63, wid = threadIdx.x >> 6;
    if (lane == 0) wsum[wid] = ld;
    __syncthreads();
    if (threadIdx.x == 0)
        blocksums[blockIdx.x] = (wsum[0] + wsum[1]) + (wsum[2] + wsum[3]);
}

__global__ __launch_bounds__(256) void vq_finalize(const unsigned* __restrict__ counts,
                                                   const double* __restrict__ blocksums,
                                                   float* __restrict__ out) {
    const int tid = threadIdx.x;
    double e = 0.0;
#pragma unroll
    for (int i = 0; i < 8; ++i) {
        int k = tid + i * 256;
        float p = (float)counts[k] / 65536.0f;   // exact in fp32
        out[PROB_OFF + k] = p;
        double pd = (double)p;
        e += pd * log(pd + 1e-5);
    }
    double s = blocksums[tid];
#pragma unroll
    for (int off = 32; off > 0; off >>= 1) {
        e += __shfl_down(e, off, 64);
        s += __shfl_down(s, off, 64);
    }
    __shared__ double we[4], ws2[4];
    int lane = tid & 63, wid = tid >> 6;
    if (lane == 0) { we[wid] = e; ws2[wid] = s; }
    __syncthreads();
    if (tid == 0) {
        double entropy = (we[0] + we[1]) + (we[2] + we[3]);
        double sumsq   = (ws2[0] + ws2[1]) + (ws2[2] + ws2[3]);
        double mse     = sumsq / (double)((size_t)N_TOK * D);
        out[SCAL_OFF + 0] = (float)(1.25 * mse + 0.1 * entropy); // vq_loss
        out[SCAL_OFF + 1] = (float)mse;                          // commitment_loss
        out[SCAL_OFF + 2] = (float)mse;                          // codebook_loss
        out[SCAL_OFF + 3] = (float)exp(-entropy);                // perplexity
        out[SCAL_OFF + 4] = (float)entropy;                      // entropy_loss
    }
}

extern "C" void kernel_launch(void* const* d_in, const int* in_sizes, int n_in,
                              void* d_out, int out_size, void* d_ws, size_t ws_size,
                              hipStream_t stream) {
    const float* x   = (const float*)d_in[0];
    const float* emb = (const float*)d_in[1];
    float* out = (float*)d_out;

    char* ws = (char*)d_ws;
    float*    cnorm     = (float*)(ws + WS_CNORM);
    unsigned* counts    = (unsigned*)(ws + WS_COUNT);
    float*    cand_dist = (float*)(ws + WS_CDIST);
    int*      cand_idx  = (int*)(ws + WS_CIDX);
    double*   blocksums = (double*)(ws + WS_BSUM);

    vq_init<<<K / 256, 256, 0, stream>>>(emb, cnorm, counts, blocksums);
    vq_dist<<<(N_TOK / 256) * KSPLIT, 256, 0, stream>>>(x, emb, cnorm, cand_dist, cand_idx);
    vq_epilogue<<<N_TOK / 256, 256, 0, stream>>>(x, emb, cand_dist, cand_idx,
                                                 counts, blocksums, out);
    vq_finalize<<<1, 256, 0, stream>>>(counts, blocksums, out);
}